// Round 9
// baseline (4748.954 us; speedup 1.0000x reference)
//
#include <hip/hip_runtime.h>
#include <hip/hip_bf16.h>
#include <math.h>
#include <stdint.h>

// RNN LM forward: B=64 T=512 V=8192 E=1024 H=2048
// out = [logits (B*T*V f32) | loss (1 f32)]
#define Bb 64
#define Tt 512
#define Vv 8192
#define Ee 1024
#define Hh 2048

typedef unsigned short u16;
typedef unsigned long long u64;
typedef __attribute__((ext_vector_type(8))) short bf16x8;      // 8 bf16 (4 VGPR)
typedef __attribute__((ext_vector_type(8))) _Float16 f16x8;    // 8 f16  (4 VGPR)
typedef __attribute__((ext_vector_type(4))) float f32x4;       // MFMA C/D frag

__device__ __forceinline__ u16 f2b(float f) {               // f32 -> bf16 RNE
  unsigned u = __float_as_uint(f);
  u += 0x7FFF + ((u >> 16) & 1);
  return (u16)(u >> 16);
}
__device__ __forceinline__ float b2f(u16 h) {
  return __uint_as_float(((unsigned)h) << 16);
}
__device__ __forceinline__ u16 f2h_bits(float f) {          // f32 -> f16 bits
  union { _Float16 h; u16 u; } c;
  c.h = (_Float16)f;
  return c.u;
}
__device__ __forceinline__ u64 pack4(u16 a, u16 b, u16 c, u16 d) {
  return (u64)a | ((u64)b << 16) | ((u64)c << 32) | ((u64)d << 48);
}

// pipelined agent-coherent 16B load (sc1 = bypass XCD-L2, read L3 directly)
__device__ __forceinline__ void gload16f(f16x8& dst, const void* addr) {
  asm volatile("global_load_dwordx4 %0, %1, off sc1"
               : "=v"(dst) : "v"(addr) : "memory");
}

__device__ __forceinline__ void gll16(const u16* g, const u16* l) {
  __builtin_amdgcn_global_load_lds((__attribute__((address_space(1))) void*)g,
                                   (__attribute__((address_space(3))) void*)l, 16, 0, 0);
}

__device__ __forceinline__ float wave_max(float v) {
  #pragma unroll
  for (int d = 32; d; d >>= 1) v = fmaxf(v, __shfl_xor(v, d, 64));
  return v;
}
__device__ __forceinline__ float wave_sum(float v) {
  #pragma unroll
  for (int d = 32; d; d >>= 1) v += __shfl_xor(v, d, 64);
  return v;
}

// ---------------- prep kernels ----------------

__global__ __launch_bounds__(256)
void embed_cast(const float* __restrict__ WE, const int* __restrict__ idx,
                u16* __restrict__ emb2) {
  const int m = blockIdx.x;
  const int row = idx[m];
  const float4 v = ((const float4*)(WE + (size_t)row * Ee))[threadIdx.x];
  ushort4 hi, lo;
  hi.x = f2b(v.x); lo.x = f2b(v.x - b2f(hi.x));
  hi.y = f2b(v.y); lo.y = f2b(v.y - b2f(hi.y));
  hi.z = f2b(v.z); lo.z = f2b(v.z - b2f(hi.z));
  hi.w = f2b(v.w); lo.w = f2b(v.w - b2f(hi.w));
  u16* d = emb2 + (size_t)m * 2048;
  ((ushort4*)d)[threadIdx.x] = hi;
  ((ushort4*)(d + Ee))[threadIdx.x] = lo;
}

__global__ __launch_bounds__(256)
void transpose_cast(const float* __restrict__ src, u16* __restrict__ dst,
                    int R, int C, int dup) {
  __shared__ float tile[32][33];
  const int bi = blockIdx.x;
  const int bj = blockIdx.y;
  const int tid = threadIdx.x;
  const int r  = tid >> 3;
  const int c4 = (tid & 7) * 4;
  float4 v = *(const float4*)(src + (size_t)(bj * 32 + r) * C + bi * 32 + c4);
  tile[r][c4 + 0] = v.x; tile[r][c4 + 1] = v.y;
  tile[r][c4 + 2] = v.z; tile[r][c4 + 3] = v.w;
  __syncthreads();
  const int RL = R << dup;
  ushort4 o;
  o.x = f2b(tile[c4 + 0][r]); o.y = f2b(tile[c4 + 1][r]);
  o.z = f2b(tile[c4 + 2][r]); o.w = f2b(tile[c4 + 3][r]);
  u16* d = dst + (size_t)(bi * 32 + r) * RL + bj * 32 + c4;
  *(ushort4*)d = o;
  if (dup) *(ushort4*)(d + R) = o;
}

__global__ __launch_bounds__(256)
void transpose_cast_f16(const float* __restrict__ src, u16* __restrict__ dst,
                        int R, int C) {
  __shared__ float tile[32][33];
  const int bi = blockIdx.x;
  const int bj = blockIdx.y;
  const int tid = threadIdx.x;
  const int r  = tid >> 3;
  const int c4 = (tid & 7) * 4;
  float4 v = *(const float4*)(src + (size_t)(bj * 32 + r) * C + bi * 32 + c4);
  tile[r][c4 + 0] = v.x; tile[r][c4 + 1] = v.y;
  tile[r][c4 + 2] = v.z; tile[r][c4 + 3] = v.w;
  __syncthreads();
  ushort4 o;
  o.x = f2h_bits(tile[c4 + 0][r]); o.y = f2h_bits(tile[c4 + 1][r]);
  o.z = f2h_bits(tile[c4 + 2][r]); o.w = f2h_bits(tile[c4 + 3][r]);
  *(ushort4*)(dst + (size_t)(bi * 32 + r) * R + bj * 32 + c4) = o;
}

__global__ __launch_bounds__(256)
void h0_init(const float* __restrict__ start, u16* __restrict__ hbuf) {
  const int b = blockIdx.x;
  #pragma unroll
  for (int j = 0; j < 8; ++j) {
    int n = threadIdx.x * 8 + j;
    hbuf[(size_t)b * 2048 + n] = f2h_bits(start[n]);
  }
}

// ---------------- GEMM: 256x256 tile, BK=64, 8-phase schedule (T2+T3+T4+T5) ----
// C[M x N] = A[M x K] * Bt[N x K]^T, bf16 in, f32 accum. 512 thr = 8 waves
// (2M x 4N), per-wave 128x64 out (acc[8][4] f32x4). LDS 128KB: A/B double-
// buffered 256x64 tiles. st-XOR swizzle byte^=((row&7)<<4) on ds_read;
// inverse swizzle pre-applied to global source (LDS dest stays linear for
// global_load_lds). Per phase: ds_read frags | stage 1 half-tile (2 loads) |
// vmcnt(4) | barrier | lgkmcnt(0)+sched_barrier | setprio(1) 16 MFMA | barrier.
// Stage->consume gap >= 3 phases => vmcnt(4) everywhere (counted, never 0).
// MODE 0: f32 out + bias + fused softmax partials pm/ps[row][N/256].
// MODE 1: bf16 out t-major ([t][b][H]) + bias.
#define A0BASE 0
#define A1BASE 16384
#define B0BASE 32768
#define B1BASE 49152
#define MM(a, b, c) __builtin_amdgcn_mfma_f32_16x16x32_bf16(a, b, c, 0, 0, 0)

#define DSA(AB, MH, KS, I) \
  (*(const bf16x8*)&lds[(AB) + (wm * 128 + ((MH) * 4 + (I)) * 16 + l15) * 64 + (((KS) * 32 + l16 * 8) ^ axr)])
#define DSB(BB, KS, J) \
  (*(const bf16x8*)&lds[(BB) + (wn * 64 + (J) * 16 + l15) * 64 + (((KS) * 32 + l16 * 8) ^ axr)])

#define PHASE(ABUF, BBUF, MH, KS, RB, STG)                                   \
  {                                                                          \
    bf16x8 a0_ = DSA(ABUF, MH, KS, 0), a1_ = DSA(ABUF, MH, KS, 1),           \
           a2_ = DSA(ABUF, MH, KS, 2), a3_ = DSA(ABUF, MH, KS, 3);           \
    if (RB) {                                                                \
      b0_ = DSB(BBUF, KS, 0); b1_ = DSB(BBUF, KS, 1);                        \
      b2_ = DSB(BBUF, KS, 2); b3_ = DSB(BBUF, KS, 3);                        \
    }                                                                        \
    STG;                                                                     \
    asm volatile("s_waitcnt vmcnt(4)" ::: "memory");                         \
    __builtin_amdgcn_s_barrier();                                            \
    asm volatile("s_waitcnt lgkmcnt(0)" ::: "memory");                       \
    __builtin_amdgcn_sched_barrier(0);                                       \
    __builtin_amdgcn_s_setprio(1);                                           \
    acc[(MH)*4+0][0] = MM(a0_, b0_, acc[(MH)*4+0][0]);                       \
    acc[(MH)*4+0][1] = MM(a0_, b1_, acc[(MH)*4+0][1]);                       \
    acc[(MH)*4+0][2] = MM(a0_, b2_, acc[(MH)*4+0][2]);                       \
    acc[(MH)*4+0][3] = MM(a0_, b3_, acc[(MH)*4+0][3]);                       \
    acc[(MH)*4+1][0] = MM(a1_, b0_, acc[(MH)*4+1][0]);                       \
    acc[(MH)*4+1][1] = MM(a1_, b1_, acc[(MH)*4+1][1]);                       \
    acc[(MH)*4+1][2] = MM(a1_, b2_, acc[(MH)*4+1][2]);                       \
    acc[(MH)*4+1][3] = MM(a1_, b3_, acc[(MH)*4+1][3]);                       \
    acc[(MH)*4+2][0] = MM(a2_, b0_, acc[(MH)*4+2][0]);                       \
    acc[(MH)*4+2][1] = MM(a2_, b1_, acc[(MH)*4+2][1]);                       \
    acc[(MH)*4+2][2] = MM(a2_, b2_, acc[(MH)*4+2][2]);                       \
    acc[(MH)*4+2][3] = MM(a2_, b3_, acc[(MH)*4+2][3]);                       \
    acc[(MH)*4+3][0] = MM(a3_, b0_, acc[(MH)*4+3][0]);                       \
    acc[(MH)*4+3][1] = MM(a3_, b1_, acc[(MH)*4+3][1]);                       \
    acc[(MH)*4+3][2] = MM(a3_, b2_, acc[(MH)*4+3][2]);                       \
    acc[(MH)*4+3][3] = MM(a3_, b3_, acc[(MH)*4+3][3]);                       \
    __builtin_amdgcn_s_setprio(0);                                           \
    __builtin_amdgcn_s_barrier();                                            \
  }

template <int MODE>
__global__ __launch_bounds__(512)
void gemm256(const u16* __restrict__ A, const u16* __restrict__ Bt,
             const float* __restrict__ bias, void* __restrict__ outp,
             float* __restrict__ pm, float* __restrict__ ps,
             int M, int N, int K) {
  __shared__ u16 lds[65536];   // 128KB

  const int tid = threadIdx.x;
  const int lane = tid & 63;
  const int w = tid >> 6;          // wave 0..7
  const int wm = w >> 2;           // 0..1 (M)
  const int wn = w & 3;            // 0..3 (N)
  const int l15 = lane & 15, l16 = lane >> 4;
  const int axr = (l15 & 7) << 3;  // ds_read XOR term (u16 units)

  // XCD-aware swizzle (nwg % 8 == 0 at both call sites)
  const int nwg = gridDim.x * gridDim.y;
  const int lin = blockIdx.y * gridDim.x + blockIdx.x;
  const int swz = (lin & 7) * (nwg >> 3) + (lin >> 3);
  const int bm = swz % gridDim.x;
  const int bn = swz / gridDim.x;
  const int bm256 = bm * 256, bn256 = bn * 256;

  // staging address pieces: lane covers row-octet sj8, swizzled 16B granule scb
  const int sj8 = lane >> 3;
  const int scb = (((lane & 7) * 16) ^ ((sj8 & 7) << 4)) >> 1;   // u16 units

  // stage one 128-row half-tile (rows [r0,r0+128) of src, K-tile kt) into lbase
  #define STAGE(src, r0, kt, lbase)                                          \
    {                                                                        \
      _Pragma("unroll")                                                      \
      for (int j_ = 0; j_ < 2; ++j_) {                                       \
        const int chunk_ = w * 2 + j_;                                       \
        gll16(src + (size_t)((r0) + chunk_ * 8 + sj8) * K + (kt) * 64 + scb, \
              &lds[(lbase) + chunk_ * 512]);                                 \
      }                                                                      \
    }

  f32x4 acc[8][4];
  #pragma unroll
  for (int m = 0; m < 8; ++m)
    #pragma unroll
    for (int n = 0; n < 4; ++n)
      acc[m][n] = (f32x4){0.f, 0.f, 0.f, 0.f};
  bf16x8 b0_, b1_, b2_, b3_;

  // prologue: t0 all 4 halves + t1's A0; drain; barrier
  STAGE(Bt, bn256,       0, B0BASE);
  STAGE(Bt, bn256 + 128, 0, B0BASE + 8192);
  STAGE(A,  bm256,       0, A0BASE);
  STAGE(A,  bm256 + 128, 0, A0BASE + 8192);
  STAGE(A,  bm256,       1, A1BASE);
  asm volatile("s_waitcnt vmcnt(0)" ::: "memory");
  __builtin_amdgcn_s_barrier();

  const int NG = K >> 7;   // groups of 2 K-tiles
  for (int g = 0; g < NG; ++g) {
    const int t1 = 2 * g + 1, t2 = 2 * g + 2, t3 = 2 * g + 3;
    const bool more = (g + 1 < NG);
    PHASE(A0BASE, B0BASE, 0, 0, true,  STAGE(Bt, bn256,       t1, B1BASE))             // ph1
    PHASE(A0BASE, B0BASE, 1, 0, false, STAGE(Bt, bn256 + 128, t1, B1BASE + 8192))      // ph2
    PHASE(A0BASE, B0BASE, 0, 1, true,  STAGE(A,  bm256 + 128, t1, A1BASE + 8192))      // ph3
    PHASE(A0BASE, B0BASE, 1, 1, false, if (more) STAGE(Bt, bn256,       t2, B0BASE))   // ph4
    PHASE(A1BASE, B1BASE, 0, 0, true,  if (more) STAGE(Bt, bn256 + 128, t2, B0BASE + 8192)) // ph5
    PHASE(A1BASE, B1BASE, 1, 0, false, if (more) STAGE(A,  bm256,       t2, A0BASE))   // ph6
    PHASE(A1BASE, B1BASE, 0, 1, true,  if (more) STAGE(A,  bm256 + 128, t2, A0BASE + 8192)) // ph7
    PHASE(A1BASE, B1BASE, 1, 1, false, if (more) STAGE(A,  bm256,       t3, A1BASE))   // ph8
  }

  // ---- epilogue (last PHASE ended with s_barrier; LDS now reusable) ----
  const int c0 = bn256 + wn * 64 + l15;
  float bv[4];
  #pragma unroll
  for (int j = 0; j < 4; ++j) bv[j] = bias[c0 + j * 16];

  if (MODE == 0) {
    float* scr = (float*)lds;        // [0..1024): max, [1024..2048): sumexp
    float* outf = (float*)outp;
    #pragma unroll
    for (int fm = 0; fm < 8; ++fm) {
      #pragma unroll
      for (int q = 0; q < 4; ++q) {
        const int rl = wm * 128 + fm * 16 + l16 * 4 + q;   // 0..255
        const int row = bm256 + rl;
        float v0 = acc[fm][0][q] + bv[0];
        float v1 = acc[fm][1][q] + bv[1];
        float v2 = acc[fm][2][q] + bv[2];
        float v3 = acc[fm][3][q] + bv[3];
        outf[(size_t)row * N + c0]      = v0;
        outf[(size_t)row * N + c0 + 16] = v1;
        outf[(size_t)row * N + c0 + 32] = v2;
        outf[(size_t)row * N + c0 + 48] = v3;
        float mx = fmaxf(fmaxf(v0, v1), fmaxf(v2, v3));
        #pragma unroll
        for (int d = 1; d < 16; d <<= 1) mx = fmaxf(mx, __shfl_xor(mx, d, 64));
        float se = expf(v0 - mx) + expf(v1 - mx) + expf(v2 - mx) + expf(v3 - mx);
        #pragma unroll
        for (int d = 1; d < 16; d <<= 1) se += __shfl_xor(se, d, 64);
        if (l15 == 0) {
          scr[wn * 256 + rl] = mx;
          scr[1024 + wn * 256 + rl] = se;
        }
      }
    }
    __syncthreads();
    if (lane < 32) {
      const int rl = w * 32 + lane;
      float m0 = scr[rl], m1 = scr[256 + rl], m2 = scr[512 + rl], m3 = scr[768 + rl];
      float Mx = fmaxf(fmaxf(m0, m1), fmaxf(m2, m3));
      float S = scr[1024 + rl] * expf(m0 - Mx) + scr[1280 + rl] * expf(m1 - Mx)
              + scr[1536 + rl] * expf(m2 - Mx) + scr[1792 + rl] * expf(m3 - Mx);
      const int row = bm256 + rl;
      pm[(size_t)row * 32 + bn] = Mx;
      ps[(size_t)row * 32 + bn] = S;
    }
  } else {
    u16* outh = (u16*)outp;
    #pragma unroll
    for (int fm = 0; fm < 8; ++fm) {
      #pragma unroll
      for (int q = 0; q < 4; ++q) {
        const int row = bm256 + wm * 128 + fm * 16 + l16 * 4 + q;
        const int b = row >> 9, t = row & 511;   // row = b*T + t
        u16* dst = outh + ((size_t)t * Bb + b) * N + c0;
        dst[0]  = f2b(acc[fm][0][q] + bv[0]);
        dst[16] = f2b(acc[fm][1][q] + bv[1]);
        dst[32] = f2b(acc[fm][2][q] + bv[2]);
        dst[48] = f2b(acc[fm][3][q] + bv[3]);
      }
    }
  }
}

// ---------------- persistent recurrence scan (r8, unchanged) ----------------
__global__ __launch_bounds__(512, 2)
void rnn_scan(const u16* __restrict__ WhT, const u16* __restrict__ xp,
              u16* __restrict__ hbuf, u16* __restrict__ hidden,
              unsigned* __restrict__ sync) {
  __shared__ u16 whi[65536];     // 128KB f16 bits: frag(c2,kt) base (c2*64+kt)*512 u16
  __shared__ float red[4096];    // 16KB

  const int bid = blockIdx.x;
  const int g = bid >> 6;
  const int colg = bid & 63;
  const int rowbase = g * 16;
  const int col0 = colg * 32;
  const int tid = threadIdx.x;
  const int lane = tid & 63;
  const int w = tid >> 6;

  for (int i = tid; i < 8192; i += 512) {
    const int ch = i & 3;
    const int cl = (i >> 2) & 15;
    const int kt = (i >> 6) & 63;
    const int c2 = (i >> 12) & 1;
    bf16x8 v = *(const bf16x8*)(WhT + (size_t)(col0 + c2 * 16 + cl) * 2048 + kt * 32 + ch * 8);
    *(bf16x8*)&whi[(size_t)(c2 * 64 + kt) * 512 + ch * 128 + cl * 8] = v;
  }
  __syncthreads();

  unsigned* cnt = sync + g * 64;
  bool dead = false;
  const int hrow = rowbase + (lane & 15);

  ushort4 xv = {0, 0, 0, 0};
  if (w < 2)
    xv = *(const ushort4*)(xp + (size_t)hrow * 2048 + col0 + w * 16 + (lane >> 4) * 4);

  for (int t = 0; t < Tt; ++t) {
    const u16* hp = hbuf + (size_t)(t & 1) * (64 * 2048);
    u16*       hn = hbuf + (size_t)((t + 1) & 1) * (64 * 2048);

    f16x8 qh[8];
    const u16* hb = hp + (size_t)hrow * 2048 + (lane >> 4) * 8;
    #pragma unroll
    for (int kt = 0; kt < 8; ++kt)
      gload16f(qh[kt], hb + (w * 8 + kt) * 32);
    asm volatile("s_waitcnt vmcnt(0)" ::: "memory");
    __builtin_amdgcn_sched_barrier(0);

    f32x4 a0 = (f32x4){0.f, 0.f, 0.f, 0.f};
    f32x4 a1 = (f32x4){0.f, 0.f, 0.f, 0.f};
    #pragma unroll
    for (int kt = 0; kt < 8; ++kt) {
      const int ktG = w * 8 + kt;
      f16x8 w0 = *(const f16x8*)&whi[(size_t)(0 * 64 + ktG) * 512 + (lane >> 4) * 128 + (lane & 15) * 8];
      f16x8 w1 = *(const f16x8*)&whi[(size_t)(1 * 64 + ktG) * 512 + (lane >> 4) * 128 + (lane & 15) * 8];
      a0 = __builtin_amdgcn_mfma_f32_16x16x32_f16(w0, qh[kt], a0, 0, 0, 0);
      a1 = __builtin_amdgcn_mfma_f32_16x16x32_f16(w1, qh[kt], a1, 0, 0, 0);
    }

    *(f32x4*)&red[(w) * 256 + lane * 4]     = a0;
    *(f32x4*)&red[(8 + w) * 256 + lane * 4] = a1;
    __syncthreads();

    if (w < 2) {
      f32x4 ac = (f32x4){0.f, 0.f, 0.f, 0.f};
      #pragma unroll
      for (int j = 0; j < 8; ++j)
        ac += *(const f32x4*)&red[(w * 8 + j) * 256 + lane * 4];
      const int cl0 = (lane >> 4) * 4;
      u16 hf[4], hbv[4];
      #pragma unroll
      for (int qq = 0; qq < 4; ++qq) {
        float v = tanhf(ac[qq] + b2f(((const u16*)&xv)[qq]));
        hf[qq]  = f2h_bits(v);
        hbv[qq] = f2b(v);
      }
      u64 ph = pack4(hf[0], hf[1], hf[2], hf[3]);
      u64 pb = pack4(hbv[0], hbv[1], hbv[2], hbv[3]);
      u16* hd = hn + (size_t)hrow * 2048 + col0 + w * 16 + cl0;
      __hip_atomic_store((u64*)hd, ph, __ATOMIC_RELAXED, __HIP_MEMORY_SCOPE_AGENT);
      *(u64*)(hidden + ((size_t)hrow * Tt + t) * Hh + col0 + w * 16 + cl0) = pb;
    }

    __syncthreads();
    if (w < 2 && t + 1 < Tt)
      xv = *(const ushort4*)(xp + ((size_t)(t + 1) * Bb + hrow) * 2048 + col0 + w * 16 + (lane >> 4) * 4);
    if (tid == 0) {
      unsigned old = __hip_atomic_fetch_add(cnt, 1u, __ATOMIC_RELAXED, __HIP_MEMORY_SCOPE_AGENT);
      if (old != (unsigned)(t * 64 + 63) && !dead) {
        unsigned polls = 0;
        while (__hip_atomic_load(cnt, __ATOMIC_RELAXED, __HIP_MEMORY_SCOPE_AGENT)
               < (unsigned)((t + 1) * 64)) {
          if (++polls > 4000000u) { dead = true; break; }
        }
      }
    }
    __syncthreads();
  }
}

// ---------------- loss ----------------

__global__ __launch_bounds__(256)
void nll_from_partials(const float* __restrict__ pm, const float* __restrict__ ps,
                       const float* __restrict__ logits, const int* __restrict__ tgt,
                       float* __restrict__ nll) {
  const int r = blockIdx.x * 4 + (threadIdx.x >> 6);
  const int lane = threadIdx.x & 63;
  float m = (lane < 32) ? pm[(size_t)r * 32 + lane] : -1e30f;
  float s = (lane < 32) ? ps[(size_t)r * 32 + lane] : 0.f;
  float M = wave_max(m);
  float S = wave_sum(s * expf(m - M));
  if (lane == 0) {
    const int tg = tgt[r];
    float o = 0.f;
    if (tg != -1) o = M + logf(S) - logits[(size_t)r * Vv + tg];
    nll[r] = o;
  }
}

__global__ __launch_bounds__(256)
void loss_reduce(const float* __restrict__ nll, const int* __restrict__ tgt,
                 float* __restrict__ out) {
  const int tid = threadIdx.x;
  float s = 0.f, c = 0.f;
  for (int i = tid; i < Bb * Tt; i += 256) {
    s += nll[i];
    c += (tgt[i] != -1) ? 1.f : 0.f;
  }
  s = wave_sum(s);
  c = wave_sum(c);
  __shared__ float as_[4], ac_[4];
  const int w = tid >> 6;
  if ((tid & 63) == 0) { as_[w] = s; ac_[w] = c; }
  __syncthreads();
  if (tid == 0) {
    float S = as_[0] + as_[1] + as_[2] + as_[3];
    float C = ac_[0] + ac_[1] + ac_[2] + ac_[3];
    out[0] = S / fmaxf(C, 1.f);
  }
}

// ---------------- launch ----------------

extern "C" void kernel_launch(void* const* d_in, const int* in_sizes, int n_in,
                              void* d_out, int out_size, void* d_ws, size_t ws_size,
                              hipStream_t stream) {
  const int*   idx    = (const int*)d_in[0];
  const int*   tgt    = (const int*)d_in[1];
  const float* W_E    = (const float*)d_in[2];
  const float* start  = (const float*)d_in[3];
  const float* W_xh   = (const float*)d_in[4];
  const float* b_xh   = (const float*)d_in[5];
  const float* W_head = (const float*)d_in[6];
  const float* b_head = (const float*)d_in[7];

  char* ws = (char*)d_ws;
  u16*      emb2   = (u16*)(ws);                                  // 32768x2048 bf16 = 128MB
  u16*      hidden = (u16*)(ws);                                  // (alias)
  u16*      xproj  = (u16*)(ws + (size_t)128 * 1024 * 1024);      // [T][B][H] bf16 = 128MB
  float*    pm     = (float*)(ws + (size_t)128 * 1024 * 1024);    // 32768x32 f32 = 4MB (alias)
  float*    ps     = (float*)(ws + (size_t)136 * 1024 * 1024);    // 32768x32 f32 = 4MB (alias)
  u16*      WheadT = (u16*)(ws + (size_t)256 * 1024 * 1024);      // 8192x2048 bf16 = 32MB
  u16*      WhT    = (u16*)(ws + (size_t)288 * 1024 * 1024);      // 2048x2048 f16 = 8MB
  u16*      WxT2   = (u16*)(ws + (size_t)304 * 1024 * 1024);      // 2048x2048 bf16 = 8MB
  u16*      hbuf   = (u16*)(ws + (size_t)312 * 1024 * 1024);      // 2x64x2048 f16 = 512KB
  float*    nll    = (float*)(ws + (size_t)313 * 1024 * 1024);    // 32768 f32
  unsigned* sync   = (unsigned*)(ws + (size_t)313 * 1024 * 1024 + 128 * 1024);

  embed_cast<<<Bb * Tt, 256, 0, stream>>>(W_E, idx, emb2);
  transpose_cast<<<dim3(Hh / 32, Ee / 32), 256, 0, stream>>>(W_xh, WxT2, Ee, Hh, 1);
  transpose_cast_f16<<<dim3(Hh / 32, Hh / 32), 256, 0, stream>>>(W_xh + (size_t)Ee * Hh, WhT, Hh, Hh);
  transpose_cast<<<dim3(Vv / 32, Hh / 32), 256, 0, stream>>>(W_head, WheadT, Hh, Vv, 0);
  h0_init<<<Bb, 256, 0, stream>>>(start, hbuf);
  hipMemsetAsync(sync, 0, 1024, stream);

  // xproj = [emb_hi|emb_lo] @ [Wx;Wx] + b_xh   (K=2048 effective)
  gemm256<1><<<dim3(128, 8), 512, 0, stream>>>(emb2, WxT2, b_xh, xproj, nullptr, nullptr,
                                               Bb * Tt, Hh, 2048);

  // persistent scan: 256 blocks (1/CU), 512 threads, Wh resident in LDS (f16)
  rnn_scan<<<256, 512, 0, stream>>>(WhT, xproj, hbuf, hidden, sync);

  // logits = hidden @ W_head + b_head -> d_out, + fused softmax partials
  gemm256<0><<<dim3(128, 32), 512, 0, stream>>>(hidden, WheadT, b_head, d_out, pm, ps,
                                                Bb * Tt, Vv, 2048);

  nll_from_partials<<<Bb * Tt / 4, 256, 0, stream>>>(pm, ps, (const float*)d_out, tgt, nll);
  loss_reduce<<<1, 256, 0, stream>>>(nll, tgt, (float*)d_out + ((size_t)out_size - 1));
}

// Round 10
// 4375.843 us; speedup vs baseline: 1.0853x; 1.0853x over previous
//
#include <hip/hip_runtime.h>
#include <hip/hip_bf16.h>
#include <math.h>
#include <stdint.h>

// RNN LM forward: B=64 T=512 V=8192 E=1024 H=2048
// out = [logits (B*T*V f32) | loss (1 f32)]
#define Bb 64
#define Tt 512
#define Vv 8192
#define Ee 1024
#define Hh 2048

typedef unsigned short u16;
typedef unsigned long long u64;
typedef __attribute__((ext_vector_type(8))) short bf16x8;      // 8 bf16 (4 VGPR)
typedef __attribute__((ext_vector_type(8))) _Float16 f16x8;    // 8 f16  (4 VGPR)
typedef __attribute__((ext_vector_type(4))) float f32x4;       // MFMA C/D frag

__device__ __forceinline__ u16 f2b(float f) {               // f32 -> bf16 RNE
  unsigned u = __float_as_uint(f);
  u += 0x7FFF + ((u >> 16) & 1);
  return (u16)(u >> 16);
}
__device__ __forceinline__ float b2f(u16 h) {
  return __uint_as_float(((unsigned)h) << 16);
}
__device__ __forceinline__ u16 f2h_bits(float f) {          // f32 -> f16 bits
  union { _Float16 h; u16 u; } c;
  c.h = (_Float16)f;
  return c.u;
}
__device__ __forceinline__ u64 pack4(u16 a, u16 b, u16 c, u16 d) {
  return (u64)a | ((u64)b << 16) | ((u64)c << 32) | ((u64)d << 48);
}

// pipelined agent-coherent 16B load (sc1 = bypass XCD-L2, read L3 directly)
__device__ __forceinline__ void gload16f(f16x8& dst, const void* addr) {
  asm volatile("global_load_dwordx4 %0, %1, off sc1"
               : "=v"(dst) : "v"(addr) : "memory");
}

__device__ __forceinline__ void gll16(const u16* g, const u16* l) {
  __builtin_amdgcn_global_load_lds((__attribute__((address_space(1))) void*)g,
                                   (__attribute__((address_space(3))) void*)l, 16, 0, 0);
}

__device__ __forceinline__ float wave_max(float v) {
  #pragma unroll
  for (int d = 32; d; d >>= 1) v = fmaxf(v, __shfl_xor(v, d, 64));
  return v;
}
__device__ __forceinline__ float wave_sum(float v) {
  #pragma unroll
  for (int d = 32; d; d >>= 1) v += __shfl_xor(v, d, 64);
  return v;
}

// ---------------- prep kernels ----------------

// gather W_E rows by idx -> f16 (r10: single f16 stream; hi/lo split was
// over-precision — f16 emb err 2.4e-4 rel -> ~1e-5 abs on xproj, far below
// the 9.77e-4 head-GEMM bf16 floor. Halves xproj-GEMM K and staging.)
__global__ __launch_bounds__(256)
void embed_cast_f16(const float* __restrict__ WE, const int* __restrict__ idx,
                    u16* __restrict__ emb) {
  const int m = blockIdx.x;
  const int row = idx[m];
  const float4 v = ((const float4*)(WE + (size_t)row * Ee))[threadIdx.x];
  ushort4 o;
  o.x = f2h_bits(v.x); o.y = f2h_bits(v.y);
  o.z = f2h_bits(v.z); o.w = f2h_bits(v.w);
  ((ushort4*)(emb + (size_t)m * Ee))[threadIdx.x] = o;
}

// src[R][C] f32 -> dst[C][R] bf16 (transpose+cast) — for W_head
__global__ __launch_bounds__(256)
void transpose_cast(const float* __restrict__ src, u16* __restrict__ dst,
                    int R, int C) {
  __shared__ float tile[32][33];
  const int bi = blockIdx.x;
  const int bj = blockIdx.y;
  const int tid = threadIdx.x;
  const int r  = tid >> 3;
  const int c4 = (tid & 7) * 4;
  float4 v = *(const float4*)(src + (size_t)(bj * 32 + r) * C + bi * 32 + c4);
  tile[r][c4 + 0] = v.x; tile[r][c4 + 1] = v.y;
  tile[r][c4 + 2] = v.z; tile[r][c4 + 3] = v.w;
  __syncthreads();
  ushort4 o;
  o.x = f2b(tile[c4 + 0][r]); o.y = f2b(tile[c4 + 1][r]);
  o.z = f2b(tile[c4 + 2][r]); o.w = f2b(tile[c4 + 3][r]);
  *(ushort4*)(dst + (size_t)(bi * 32 + r) * R + bj * 32 + c4) = o;
}

// src[R][C] f32 -> dst[C][R] f16 bits (transpose + f16 cast) — for Wh, Wx
__global__ __launch_bounds__(256)
void transpose_cast_f16(const float* __restrict__ src, u16* __restrict__ dst,
                        int R, int C) {
  __shared__ float tile[32][33];
  const int bi = blockIdx.x;
  const int bj = blockIdx.y;
  const int tid = threadIdx.x;
  const int r  = tid >> 3;
  const int c4 = (tid & 7) * 4;
  float4 v = *(const float4*)(src + (size_t)(bj * 32 + r) * C + bi * 32 + c4);
  tile[r][c4 + 0] = v.x; tile[r][c4 + 1] = v.y;
  tile[r][c4 + 2] = v.z; tile[r][c4 + 3] = v.w;
  __syncthreads();
  ushort4 o;
  o.x = f2h_bits(tile[c4 + 0][r]); o.y = f2h_bits(tile[c4 + 1][r]);
  o.z = f2h_bits(tile[c4 + 2][r]); o.w = f2h_bits(tile[c4 + 3][r]);
  *(ushort4*)(dst + (size_t)(bi * 32 + r) * R + bj * 32 + c4) = o;
}

__global__ __launch_bounds__(256)
void h0_init(const float* __restrict__ start, u16* __restrict__ hbuf) {
  const int b = blockIdx.x;
  #pragma unroll
  for (int j = 0; j < 8; ++j) {
    int n = threadIdx.x * 8 + j;
    hbuf[(size_t)b * 2048 + n] = f2h_bits(start[n]);
  }
}

// ---------------- GEMM (m97-style 128x128 tile, BK=32, 4 waves) ----------------
// C[M x N] = A[M x K] * Bt[N x K]^T, f32 accum. F16 selects f16 vs bf16 MFMA.
// MODE 0: out f32 at [row*N+col] + bias (head GEMM -> logits in d_out),
//         PLUS fused per-row softmax partials pm/ps[row][bn].
// MODE 1: out bf16 at [(t*B+b)*N+col] + bias, row = b*T+t  (xproj, t-major)
// XCD-aware block swizzle (T1): nwg % 8 == 0 for both call sites.
template <int MODE, int F16>
__global__ __launch_bounds__(256, 2)
void gemm_bt(const u16* __restrict__ A, const u16* __restrict__ Bt,
             const float* __restrict__ bias, void* __restrict__ outp,
             float* __restrict__ pm, float* __restrict__ ps,
             int M, int N, int K) {
  __shared__ u16 ldsA[128 * 32];
  __shared__ u16 ldsB[128 * 32];
  __shared__ float sm_[2][2][64];   // [wc][wr][row_local]  (MODE 0 partials)
  __shared__ float ss_[2][2][64];
  const int tid = threadIdx.x;
  const int lane = tid & 63;
  const int w = tid >> 6;
  const int wr = w >> 1, wc = w & 1;

  const int nwg = gridDim.x * gridDim.y;
  const int lin = blockIdx.y * gridDim.x + blockIdx.x;
  const int swz = (lin & 7) * (nwg >> 3) + (lin >> 3);
  const int bm = swz % gridDim.x;
  const int bn = swz / gridDim.x;

  const int srow = w * 32 + (lane >> 2);
  const int scol = (lane & 3) * 8;
  const u16* a0 = A + (size_t)(bm * 128 + srow) * K + scol;
  const u16* b0 = Bt + (size_t)(bn * 128 + srow) * K + scol;
  u16* lA0 = ldsA + w * 1024;
  u16* lA1 = ldsA + w * 1024 + 512;
  u16* lB0 = ldsB + w * 1024;
  u16* lB1 = ldsB + w * 1024 + 512;

  f32x4 acc[4][4];
  #pragma unroll
  for (int m = 0; m < 4; ++m)
    #pragma unroll
    for (int n = 0; n < 4; ++n)
      acc[m][n] = (f32x4){0.f, 0.f, 0.f, 0.f};

  const int nk = K >> 5;
  for (int kt = 0; kt < nk; ++kt) {
    __syncthreads();
    const u16* ak = a0 + kt * 32;
    const u16* bk = b0 + kt * 32;
    gll16(ak, lA0);
    gll16(ak + 16 * (size_t)K, lA1);
    gll16(bk, lB0);
    gll16(bk + 16 * (size_t)K, lB1);
    __syncthreads();
    bf16x8 af[4], bfr[4];
    #pragma unroll
    for (int i = 0; i < 4; ++i) {
      af[i]  = *(const bf16x8*)&ldsA[(wr * 64 + i * 16 + (lane & 15)) * 32 + (lane >> 4) * 8];
      bfr[i] = *(const bf16x8*)&ldsB[(wc * 64 + i * 16 + (lane & 15)) * 32 + (lane >> 4) * 8];
    }
    #pragma unroll
    for (int m = 0; m < 4; ++m)
      #pragma unroll
      for (int n = 0; n < 4; ++n) {
        if (F16) {
          acc[m][n] = __builtin_amdgcn_mfma_f32_16x16x32_f16(
              *(const f16x8*)&af[m], *(const f16x8*)&bfr[n], acc[m][n], 0, 0, 0);
        } else {
          acc[m][n] = __builtin_amdgcn_mfma_f32_16x16x32_bf16(af[m], bfr[n], acc[m][n], 0, 0, 0);
        }
      }
  }

  // epilogue: D col = lane&15, row = (lane>>4)*4 + q
  const int r0 = bm * 128 + wr * 64 + (lane >> 4) * 4;
  const int c0 = bn * 128 + wc * 64 + (lane & 15);

  if (MODE == 0) {
    float bv[4];
    #pragma unroll
    for (int n = 0; n < 4; ++n) bv[n] = bias[c0 + n * 16];
    #pragma unroll
    for (int m = 0; m < 4; ++m) {
      #pragma unroll
      for (int q = 0; q < 4; ++q) {
        const int row = r0 + m * 16 + q;
        float v[4];
        float mx = -1e30f;
        #pragma unroll
        for (int n = 0; n < 4; ++n) {
          v[n] = acc[m][n][q] + bv[n];
          ((float*)outp)[(size_t)row * N + c0 + n * 16] = v[n];
          mx = fmaxf(mx, v[n]);
        }
        #pragma unroll
        for (int d = 1; d < 16; d <<= 1) mx = fmaxf(mx, __shfl_xor(mx, d, 64));
        float se = 0.f;
        #pragma unroll
        for (int n = 0; n < 4; ++n) se += expf(v[n] - mx);
        #pragma unroll
        for (int d = 1; d < 16; d <<= 1) se += __shfl_xor(se, d, 64);
        if ((lane & 15) == 0) {
          const int rl = m * 16 + (lane >> 4) * 4 + q;
          sm_[wc][wr][rl] = mx;
          ss_[wc][wr][rl] = se;
        }
      }
    }
    __syncthreads();
    if (w < 2) {   // wave w combines wc halves for rows [bm*128 + w*64, +64)
      float m0 = sm_[0][w][lane], m1 = sm_[1][w][lane];
      float s0 = ss_[0][w][lane], s1 = ss_[1][w][lane];
      float Mx = fmaxf(m0, m1);
      float S = s0 * expf(m0 - Mx) + s1 * expf(m1 - Mx);
      const int row = bm * 128 + w * 64 + lane;
      pm[(size_t)row * 64 + bn] = Mx;
      ps[(size_t)row * 64 + bn] = S;
    }
  } else {
    #pragma unroll
    for (int n = 0; n < 4; ++n) {
      const int col = c0 + n * 16;
      const float bv = bias[col];
      #pragma unroll
      for (int m = 0; m < 4; ++m) {
        #pragma unroll
        for (int q = 0; q < 4; ++q) {
          const int row = r0 + m * 16 + q;
          float v = acc[m][n][q] + bv;
          const int b = row >> 9, t = row & 511;   // row = b*T + t
          ((u16*)outp)[((size_t)t * Bb + b) * N + col] = f2b(v);
        }
      }
    }
  }
}

// ---------------- persistent recurrence scan (r8, unchanged) ----------------
// 256 blocks x 512 thr (8 waves), 1 block/CU (144KB LDS). Wh f16 in LDS for
// all 512 steps; h = single f16 stream, ping-pong in global via sc1.
// Sync (A/B-measured r2-r8): relaxed single monotonic counter, poll the
// counter itself; agent acq/rel = L2 wb/inv (never in hot loop); flag arrays
// and arrival trees both regress.
__global__ __launch_bounds__(512, 2)
void rnn_scan(const u16* __restrict__ WhT, const u16* __restrict__ xp,
              u16* __restrict__ hbuf, u16* __restrict__ hidden,
              unsigned* __restrict__ sync) {
  __shared__ u16 whi[65536];     // 128KB f16 bits: frag(c2,kt) base (c2*64+kt)*512 u16
  __shared__ float red[4096];    // 16KB

  const int bid = blockIdx.x;
  const int g = bid >> 6;
  const int colg = bid & 63;
  const int rowbase = g * 16;
  const int col0 = colg * 32;
  const int tid = threadIdx.x;
  const int lane = tid & 63;
  const int w = tid >> 6;

  for (int i = tid; i < 8192; i += 512) {
    const int ch = i & 3;
    const int cl = (i >> 2) & 15;
    const int kt = (i >> 6) & 63;
    const int c2 = (i >> 12) & 1;
    bf16x8 v = *(const bf16x8*)(WhT + (size_t)(col0 + c2 * 16 + cl) * 2048 + kt * 32 + ch * 8);
    *(bf16x8*)&whi[(size_t)(c2 * 64 + kt) * 512 + ch * 128 + cl * 8] = v;
  }
  __syncthreads();

  unsigned* cnt = sync + g * 64;
  bool dead = false;
  const int hrow = rowbase + (lane & 15);

  ushort4 xv = {0, 0, 0, 0};
  if (w < 2)
    xv = *(const ushort4*)(xp + (size_t)hrow * 2048 + col0 + w * 16 + (lane >> 4) * 4);

  for (int t = 0; t < Tt; ++t) {
    const u16* hp = hbuf + (size_t)(t & 1) * (64 * 2048);
    u16*       hn = hbuf + (size_t)((t + 1) & 1) * (64 * 2048);

    f16x8 qh[8];
    const u16* hb = hp + (size_t)hrow * 2048 + (lane >> 4) * 8;
    #pragma unroll
    for (int kt = 0; kt < 8; ++kt)
      gload16f(qh[kt], hb + (w * 8 + kt) * 32);
    asm volatile("s_waitcnt vmcnt(0)" ::: "memory");
    __builtin_amdgcn_sched_barrier(0);

    f32x4 a0 = (f32x4){0.f, 0.f, 0.f, 0.f};
    f32x4 a1 = (f32x4){0.f, 0.f, 0.f, 0.f};
    #pragma unroll
    for (int kt = 0; kt < 8; ++kt) {
      const int ktG = w * 8 + kt;
      f16x8 w0 = *(const f16x8*)&whi[(size_t)(0 * 64 + ktG) * 512 + (lane >> 4) * 128 + (lane & 15) * 8];
      f16x8 w1 = *(const f16x8*)&whi[(size_t)(1 * 64 + ktG) * 512 + (lane >> 4) * 128 + (lane & 15) * 8];
      a0 = __builtin_amdgcn_mfma_f32_16x16x32_f16(w0, qh[kt], a0, 0, 0, 0);
      a1 = __builtin_amdgcn_mfma_f32_16x16x32_f16(w1, qh[kt], a1, 0, 0, 0);
    }

    *(f32x4*)&red[(w) * 256 + lane * 4]     = a0;
    *(f32x4*)&red[(8 + w) * 256 + lane * 4] = a1;
    __syncthreads();

    if (w < 2) {
      f32x4 ac = (f32x4){0.f, 0.f, 0.f, 0.f};
      #pragma unroll
      for (int j = 0; j < 8; ++j)
        ac += *(const f32x4*)&red[(w * 8 + j) * 256 + lane * 4];
      const int cl0 = (lane >> 4) * 4;
      u16 hf[4], hbv[4];
      #pragma unroll
      for (int qq = 0; qq < 4; ++qq) {
        float v = tanhf(ac[qq] + b2f(((const u16*)&xv)[qq]));
        hf[qq]  = f2h_bits(v);
        hbv[qq] = f2b(v);
      }
      u64 ph = pack4(hf[0], hf[1], hf[2], hf[3]);
      u64 pb = pack4(hbv[0], hbv[1], hbv[2], hbv[3]);
      u16* hd = hn + (size_t)hrow * 2048 + col0 + w * 16 + cl0;
      __hip_atomic_store((u64*)hd, ph, __ATOMIC_RELAXED, __HIP_MEMORY_SCOPE_AGENT);
      *(u64*)(hidden + ((size_t)hrow * Tt + t) * Hh + col0 + w * 16 + cl0) = pb;
    }

    __syncthreads();
    if (w < 2 && t + 1 < Tt)
      xv = *(const ushort4*)(xp + ((size_t)(t + 1) * Bb + hrow) * 2048 + col0 + w * 16 + (lane >> 4) * 4);
    if (tid == 0) {
      unsigned old = __hip_atomic_fetch_add(cnt, 1u, __ATOMIC_RELAXED, __HIP_MEMORY_SCOPE_AGENT);
      if (old != (unsigned)(t * 64 + 63) && !dead) {
        unsigned polls = 0;
        while (__hip_atomic_load(cnt, __ATOMIC_RELAXED, __HIP_MEMORY_SCOPE_AGENT)
               < (unsigned)((t + 1) * 64)) {
          if (++polls > 4000000u) { dead = true; break; }
        }
      }
    }
    __syncthreads();
  }
}

// ---------------- loss ----------------

__global__ __launch_bounds__(256)
void nll_from_partials(const float* __restrict__ pm, const float* __restrict__ ps,
                       const float* __restrict__ logits, const int* __restrict__ tgt,
                       float* __restrict__ nll) {
  const int r = blockIdx.x * 4 + (threadIdx.x >> 6);
  const int lane = threadIdx.x & 63;
  float m = pm[(size_t)r * 64 + lane];
  float s = ps[(size_t)r * 64 + lane];
  float M = wave_max(m);
  float S = wave_sum(s * expf(m - M));
  if (lane == 0) {
    const int tg = tgt[r];
    float o = 0.f;
    if (tg != -1) o = M + logf(S) - logits[(size_t)r * Vv + tg];
    nll[r] = o;
  }
}

__global__ __launch_bounds__(256)
void loss_reduce(const float* __restrict__ nll, const int* __restrict__ tgt,
                 float* __restrict__ out) {
  const int tid = threadIdx.x;
  float s = 0.f, c = 0.f;
  for (int i = tid; i < Bb * Tt; i += 256) {
    s += nll[i];
    c += (tgt[i] != -1) ? 1.f : 0.f;
  }
  s = wave_sum(s);
  c = wave_sum(c);
  __shared__ float as_[4], ac_[4];
  const int w = tid >> 6;
  if ((tid & 63) == 0) { as_[w] = s; ac_[w] = c; }
  __syncthreads();
  if (tid == 0) {
    float S = as_[0] + as_[1] + as_[2] + as_[3];
    float C = ac_[0] + ac_[1] + ac_[2] + ac_[3];
    out[0] = S / fmaxf(C, 1.f);
  }
}

// ---------------- launch ----------------

extern "C" void kernel_launch(void* const* d_in, const int* in_sizes, int n_in,
                              void* d_out, int out_size, void* d_ws, size_t ws_size,
                              hipStream_t stream) {
  const int*   idx    = (const int*)d_in[0];
  const int*   tgt    = (const int*)d_in[1];
  const float* W_E    = (const float*)d_in[2];
  const float* start  = (const float*)d_in[3];
  const float* W_xh   = (const float*)d_in[4];
  const float* b_xh   = (const float*)d_in[5];
  const float* W_head = (const float*)d_in[6];
  const float* b_head = (const float*)d_in[7];

  // workspace layout (~314 MB). emb16 (dead after xproj GEMM) aliases hidden.
  // pm/ps (head-GEMM softmax partials) alias xproj (dead after rnn_scan).
  char* ws = (char*)d_ws;
  u16*      emb16  = (u16*)(ws);                                  // 32768x1024 f16 = 64MB
  u16*      hidden = (u16*)(ws);                                  // 32768x2048 bf16 = 128MB (alias)
  u16*      xproj  = (u16*)(ws + (size_t)128 * 1024 * 1024);      // [T][B][H] bf16 = 128MB
  float*    pm     = (float*)(ws + (size_t)128 * 1024 * 1024);    // 32768x64 f32 = 8MB (alias)
  float*    ps     = (float*)(ws + (size_t)136 * 1024 * 1024);    // 32768x64 f32 = 8MB (alias)
  u16*      WheadT = (u16*)(ws + (size_t)256 * 1024 * 1024);      // 8192x2048 bf16 = 32MB
  u16*      WhT    = (u16*)(ws + (size_t)288 * 1024 * 1024);      // 2048x2048 f16 = 8MB
  u16*      WxT16  = (u16*)(ws + (size_t)304 * 1024 * 1024);      // 2048x1024 f16 = 4MB
  u16*      hbuf   = (u16*)(ws + (size_t)312 * 1024 * 1024);      // 2x64x2048 f16 = 512KB
  float*    nll    = (float*)(ws + (size_t)313 * 1024 * 1024);    // 32768 f32
  unsigned* sync   = (unsigned*)(ws + (size_t)313 * 1024 * 1024 + 128 * 1024);

  embed_cast_f16<<<Bb * Tt, 256, 0, stream>>>(W_E, idx, emb16);
  transpose_cast_f16<<<dim3(Hh / 32, Ee / 32), 256, 0, stream>>>(W_xh, WxT16, Ee, Hh);
  transpose_cast_f16<<<dim3(Hh / 32, Hh / 32), 256, 0, stream>>>(W_xh + (size_t)Ee * Hh, WhT, Hh, Hh);
  transpose_cast<<<dim3(Vv / 32, Hh / 32), 256, 0, stream>>>(W_head, WheadT, Hh, Vv);
  h0_init<<<Bb, 256, 0, stream>>>(start, hbuf);
  hipMemsetAsync(sync, 0, 1024, stream);

  // xproj = emb_f16 @ Wx_f16 + b_xh   (K=1024, f16 MFMA)
  gemm_bt<1, 1><<<dim3(256, 16), 256, 0, stream>>>(emb16, WxT16, b_xh, xproj, nullptr, nullptr,
                                                   Bb * Tt, Hh, 1024);

  // persistent scan: 256 blocks (1/CU), 512 threads, Wh resident in LDS (f16)
  rnn_scan<<<256, 512, 0, stream>>>(WhT, xproj, hbuf, hidden, sync);

  // logits = hidden @ W_head + b_head -> d_out, + fused softmax partials
  gemm_bt<0, 0><<<dim3(256, 64), 256, 0, stream>>>(hidden, WheadT, b_head, d_out, pm, ps,
                                                   Bb * Tt, Vv, 2048);

  nll_from_partials<<<Bb * Tt / 4, 256, 0, stream>>>(pm, ps, (const float*)d_out, tgt, nll);
  loss_reduce<<<1, 256, 0, stream>>>(nll, tgt, (float*)d_out + ((size_t)out_size - 1));
}